// Round 8
// baseline (1395.597 us; speedup 1.0000x reference)
//
#include <hip/hip_runtime.h>

// Caps layer: B=256 batches, S=512 input caps, D=256 in-dim, NC=16, DC=32, O=512.
// R8 change: occupancy via MORE BLOCKS. R1 (155us) is latency-bound at 2
// waves/SIMD (VALU 21%, HBM 19%, Mfma 0.5%, occ 22%); the 1024-thread route
// is closed (R2-R5: allocator pins 64 VGPR, 420MB spill, 4 mechanisms failed).
// R6/R7 MFMA-y variants paid more in x-transpose staging than saved (174/242).
// New: TWO 512-thread blocks per batch (grid=512 -> 2 blocks/CU -> 4 waves/
// SIMD) in the 512-thread regime where the allocator behaves (R1: 124 VGPR).
// Block half h owns s in [h*256, h*256+256) and o in [h*256, h*256+256).
// Coupling per iter: partial y (16KB) + half z-slab (4KB), exchanged through
// d_ws (agent-scope atomics + epoch counters; ~10.5 MB used). Race-free by
// the alternating y/z handshakes; deadlock-free: __launch_bounds__(512,4)
// forces <=128 VGPR so 2 blocks/CU always fit (35.3KB LDS x2 fits too).
// Factorized routing (u_hat never materialized):
//   y[n][D]   = sum_s c[n][s] x[s][D]     (f32 VALU, R1's exact math)
//   outputs   = squash_d( y[n] . W[:, n*32+d] )
//   z[n][D]   = sum_d W[D][n*32+d] outputs[n][d]
//   b[n][s]   = sum_D x[s][D] z[n][D]     (MFMA 16x16x32 bf16, f32 acc)

#define S_ 512
#define D_ 256
#define O_ 512

typedef __attribute__((ext_vector_type(8))) short short8;
typedef __attribute__((ext_vector_type(4))) float floatx4;

__device__ __forceinline__ unsigned short f2b(float f) {
  union { float ff; unsigned int i; } v; v.ff = f;
  unsigned int u = v.i;
  return (unsigned short)((u + 0x7FFFu + ((u >> 16) & 1u)) >> 16);
}

__global__ __launch_bounds__(512, 4) void caps_kernel(
    const float* __restrict__ x, const float* __restrict__ W,
    float* __restrict__ out, unsigned* __restrict__ ws)
{
  // LDS (35328 B; x2 blocks = 70.6 KB/CU):
  //   ytmp f32 16x260 = 16640 B: y[n][D] (own partial, then full after exch)
  //   zb   u16 16x264 =  8448 B: z bf16 (528 B rows, MFMA A-frag source)
  //   outp f32 512    =  2048 B (only own half's o-range valid)
  //   cbuf f32 8x256  =  8192 B: per-wave c-tile [16n][16s]; iter-0 rowsum
  //                              strips; squash partial sums
  __shared__ __align__(16) float ytmp[16 * 260];
  __shared__ __align__(16) unsigned short zb[16 * 264];
  __shared__ __align__(16) float outp[O_];
  __shared__ __align__(16) float cbuf[8 * 256];

  const int tid  = threadIdx.x;
  const int wave = tid >> 6;
  const int lane = tid & 63;
  const int l15  = lane & 15;
  const int l4   = lane >> 4;
  const int pair = blockIdx.x >> 1;      // batch index
  const int half = blockIdx.x & 1;       // s/o half
  const int sbase = half << 8;
  const float* xb = x + (size_t)pair * (S_ * D_);

  // ws layout: ycnt[256] u32 | zcnt[256] u32 | pad to 4096B |
  //            yext [256][2][4096] f32 (8 MB) | zext [256][2][1024] u32 (2 MB)
  unsigned* ycnt = ws;
  unsigned* zcnt = ws + 256;
  float* yext = (float*)((char*)ws + 4096);
  unsigned* zext = (unsigned*)((char*)ws + 4096 + (size_t)512 * 4096 * 4);
  float* myY = yext + ((size_t)pair * 2 + half) * 4096;
  const float* pY = yext + ((size_t)pair * 2 + (half ^ 1)) * 4096;
  unsigned* myZ = zext + ((size_t)pair * 2 + half) * 1024;
  const unsigned* pZ = zext + ((size_t)pair * 2 + (half ^ 1)) * 1024;

  for (int it = 0; it < 3; ++it) {
    if (it == 0) {
      // ---- iter 0: c=1/16 uniform -> partial y = (1/16)*rowsum(own 256 s) ----
      float a0 = 0.f, a1 = 0.f, a2 = 0.f, a3 = 0.f;
      #pragma unroll 4
      for (int r = 0; r < 32; ++r) {
        const int s = sbase + (wave << 5) + r;
        const float4 xv = *(const float4*)(xb + s * D_ + (lane << 2));
        a0 += xv.x; a1 += xv.y; a2 += xv.z; a3 += xv.w;
      }
      *(float4*)(cbuf + (wave << 8) + (lane << 2)) = make_float4(a0, a1, a2, a3);
      __syncthreads();
      if (tid < 256) {
        float v = 0.f;
        #pragma unroll
        for (int w = 0; w < 8; ++w) v += cbuf[(w << 8) + tid];
        v *= 0.0625f;
        #pragma unroll
        for (int n = 0; n < 16; ++n) ytmp[n * 260 + tid] = v;
      }
      __syncthreads();
    } else {
      // ---- FUSED pass (own 256 s): per 16-s subtile: MFMA b -> softmax -> y ----
      float acc[16][4];
      #pragma unroll
      for (int n = 0; n < 16; ++n) { acc[n][0]=0.f; acc[n][1]=0.f; acc[n][2]=0.f; acc[n][3]=0.f; }
      float* cw = cbuf + (wave << 8);   // wave-private c-tile [16n][16s]

      #pragma unroll 1
      for (int t = 0; t < 2; ++t) {
        const int s0 = sbase + (wave << 5) + (t << 4);
        floatx4 C = {0.f, 0.f, 0.f, 0.f};
        #pragma unroll
        for (int k = 0; k < 8; ++k) {
          // A-frag: z[m=l15][k*32 + l4*8 + j] from LDS (full zb after exchange)
          const short8 A = *(const short8*)(zb + l15 * 264 + (k << 5) + (l4 << 3));
          // B-frag: x[s0+l15][k*32 + l4*8 + j] fp32 global -> bf16
          const float* xp = xb + (s0 + l15) * D_ + (k << 5) + (l4 << 3);
          const float4 xv0 = *(const float4*)xp;
          const float4 xv1 = *(const float4*)(xp + 4);
          short8 Bf;
          Bf[0] = (short)f2b(xv0.x); Bf[1] = (short)f2b(xv0.y);
          Bf[2] = (short)f2b(xv0.z); Bf[3] = (short)f2b(xv0.w);
          Bf[4] = (short)f2b(xv1.x); Bf[5] = (short)f2b(xv1.y);
          Bf[6] = (short)f2b(xv1.z); Bf[7] = (short)f2b(xv1.w);
          C = __builtin_amdgcn_mfma_f32_16x16x32_bf16(A, Bf, C, 0, 0, 0);
        }
        // C/D layout: col = l15 (s), row = l4*4 + rg (n).
        float m = fmaxf(fmaxf(C[0], C[1]), fmaxf(C[2], C[3]));
        m = fmaxf(m, __shfl_xor(m, 16, 64));
        m = fmaxf(m, __shfl_xor(m, 32, 64));
        const float e0 = __expf(C[0] - m), e1 = __expf(C[1] - m);
        const float e2 = __expf(C[2] - m), e3 = __expf(C[3] - m);
        float sm = e0 + e1 + e2 + e3;
        sm += __shfl_xor(sm, 16, 64);
        sm += __shfl_xor(sm, 32, 64);
        const float inv = 1.f / sm;
        const int nb = l4 << 2;
        cw[(nb + 0) * 16 + l15] = e0 * inv;
        cw[(nb + 1) * 16 + l15] = e1 * inv;
        cw[(nb + 2) * 16 + l15] = e2 * inv;
        cw[(nb + 3) * 16 + l15] = e3 * inv;
        // same-wave LDS RAW: drain writes; "memory" clobber pins ordering
        asm volatile("s_waitcnt lgkmcnt(0)" ::: "memory");
        // y-acc: lane owns D-quad; x tile re-read is L1-hot (just fetched)
        #pragma unroll 1
        for (int g = 0; g < 4; ++g) {
          const float4 xv0g = *(const float4*)(xb + (s0 + (g << 2) + 0) * D_ + (lane << 2));
          const float4 xv1g = *(const float4*)(xb + (s0 + (g << 2) + 1) * D_ + (lane << 2));
          const float4 xv2g = *(const float4*)(xb + (s0 + (g << 2) + 2) * D_ + (lane << 2));
          const float4 xv3g = *(const float4*)(xb + (s0 + (g << 2) + 3) * D_ + (lane << 2));
          #pragma unroll
          for (int n = 0; n < 16; ++n) {
            const float4 c4 = *(const float4*)(cw + n * 16 + (g << 2));  // wave-uniform b128
            acc[n][0] += c4.x * xv0g.x; acc[n][1] += c4.x * xv0g.y;
            acc[n][2] += c4.x * xv0g.z; acc[n][3] += c4.x * xv0g.w;
            acc[n][0] += c4.y * xv1g.x; acc[n][1] += c4.y * xv1g.y;
            acc[n][2] += c4.y * xv1g.z; acc[n][3] += c4.y * xv1g.w;
            acc[n][0] += c4.z * xv2g.x; acc[n][1] += c4.z * xv2g.y;
            acc[n][2] += c4.z * xv2g.z; acc[n][3] += c4.z * xv2g.w;
            acc[n][0] += c4.w * xv3g.x; acc[n][1] += c4.w * xv3g.y;
            acc[n][2] += c4.w * xv3g.z; acc[n][3] += c4.w * xv3g.w;
          }
        }
      }
      // octant reduction into ytmp (8 serialized rounds; partial y for this half)
      for (int rr = 0; rr < 8; ++rr) {
        if (wave == rr) {
          #pragma unroll
          for (int n = 0; n < 16; ++n) {
            float4* p = (float4*)(ytmp + n * 260 + (lane << 2));
            if (rr == 0) { *p = make_float4(acc[n][0], acc[n][1], acc[n][2], acc[n][3]); }
            else { float4 v = *p; v.x += acc[n][0]; v.y += acc[n][1]; v.z += acc[n][2]; v.w += acc[n][3]; *p = v; }
          }
        }
        __syncthreads();
      }
    }

    // ---- y exchange: ytmp(partial) + partner partial -> full y ----
    {
      const int n8 = tid >> 5, d8 = (tid & 31) << 3;
      #pragma unroll
      for (int j = 0; j < 8; ++j)
        __hip_atomic_store(&myY[(n8 << 8) + d8 + j], ytmp[n8 * 260 + d8 + j],
                           __ATOMIC_RELAXED, __HIP_MEMORY_SCOPE_AGENT);
      __threadfence();
      __syncthreads();
      if (tid == 0) {
        __hip_atomic_fetch_add(&ycnt[pair], 1u, __ATOMIC_RELEASE, __HIP_MEMORY_SCOPE_AGENT);
        const unsigned tgt = 2u * (unsigned)(it + 1);
        while (__hip_atomic_load(&ycnt[pair], __ATOMIC_ACQUIRE, __HIP_MEMORY_SCOPE_AGENT) < tgt)
          __builtin_amdgcn_s_sleep(2);
      }
      __syncthreads();
      __threadfence();
      #pragma unroll
      for (int j = 0; j < 8; ++j)
        ytmp[n8 * 260 + d8 + j] += __hip_atomic_load(&pY[(n8 << 8) + d8 + j],
                           __ATOMIC_RELAXED, __HIP_MEMORY_SCOPE_AGENT);
      __syncthreads();
    }

    // ---- squash (own 256 o, D split across thread halves p) ----
    {
      const int ol = tid & 255;
      const int p  = tid >> 8;
      const int o  = sbase + ol;
      const int n  = o >> 5;
      float a = 0.f;
      #pragma unroll 4
      for (int i = 0; i < 16; ++i) {
        const int Db = (p << 4) + i;
        const float4 y0 = *(const float4*)(ytmp + n * 260 + (Db << 3));
        const float4 y1 = *(const float4*)(ytmp + n * 260 + (Db << 3) + 4);
        const float* wp = W + (size_t)(Db << 3) * O_ + o;   // coalesced over o
        a += y0.x * wp[0 * O_]; a += y0.y * wp[1 * O_];
        a += y0.z * wp[2 * O_]; a += y0.w * wp[3 * O_];
        a += y1.x * wp[4 * O_]; a += y1.y * wp[5 * O_];
        a += y1.z * wp[6 * O_]; a += y1.w * wp[7 * O_];
      }
      if (p) cbuf[ol] = a;
      __syncthreads();
      if (!p) {
        a += cbuf[ol];
        float ss = a * a;
        #pragma unroll
        for (int off = 1; off < 32; off <<= 1) ss += __shfl_xor(ss, off, 64);
        const float v = a / sqrtf(ss + 1e-7f);
        outp[o] = v;
        if (it == 2) out[(size_t)pair * O_ + o] = v;
      }
    }
    __syncthreads();

    if (it < 2) {
      // ---- z (own 8 n): wave owns 32 D-rows, 2 rows/step via lane halves ----
      {
        const int hl    = lane & 31;
        const int rowp  = lane >> 5;
        const int obase = sbase + (hl << 3);
        const int n_ln  = (half << 3) + (hl >> 2);
        float ov[8];
        #pragma unroll
        for (int j = 0; j < 8; ++j) ov[j] = outp[obase + j];
        for (int r = 0; r < 16; ++r) {
          const int Dd = (wave << 5) + (r << 1) + rowp;
          const float4 w0 = *(const float4*)(W + (size_t)Dd * O_ + obase);
          const float4 w1 = *(const float4*)(W + (size_t)Dd * O_ + obase + 4);
          float a = w0.x * ov[0] + w0.y * ov[1] + w0.z * ov[2] + w0.w * ov[3]
                  + w1.x * ov[4] + w1.y * ov[5] + w1.z * ov[6] + w1.w * ov[7];
          a += __shfl_xor(a, 1, 64);
          a += __shfl_xor(a, 2, 64);
          if ((lane & 3) == 0) zb[n_ln * 264 + Dd] = f2b(a);
        }
      }
      __syncthreads();

      // ---- z exchange: own 8x256 slab out, partner 8x256 slab in ----
      {
        const unsigned* zb32 = (const unsigned*)zb;   // rows: 132 u32 (264 u16)
        const int rloc = tid >> 6;                    // 0..7 local n
        const int c2   = (tid & 63) << 1;             // u32 col 0,2,..,126
        const int ng   = (half << 3) + rloc;
        __hip_atomic_store(&myZ[(rloc << 7) + c2],     zb32[ng * 132 + c2],
                           __ATOMIC_RELAXED, __HIP_MEMORY_SCOPE_AGENT);
        __hip_atomic_store(&myZ[(rloc << 7) + c2 + 1], zb32[ng * 132 + c2 + 1],
                           __ATOMIC_RELAXED, __HIP_MEMORY_SCOPE_AGENT);
        __threadfence();
        __syncthreads();
        if (tid == 0) {
          __hip_atomic_fetch_add(&zcnt[pair], 1u, __ATOMIC_RELEASE, __HIP_MEMORY_SCOPE_AGENT);
          const unsigned tgt = 2u * (unsigned)(it + 1);
          while (__hip_atomic_load(&zcnt[pair], __ATOMIC_ACQUIRE, __HIP_MEMORY_SCOPE_AGENT) < tgt)
            __builtin_amdgcn_s_sleep(2);
        }
        __syncthreads();
        __threadfence();
        unsigned* zb32w = (unsigned*)zb;
        const int np = ((half ^ 1) << 3) + rloc;
        zb32w[np * 132 + c2]     = __hip_atomic_load(&pZ[(rloc << 7) + c2],
                           __ATOMIC_RELAXED, __HIP_MEMORY_SCOPE_AGENT);
        zb32w[np * 132 + c2 + 1] = __hip_atomic_load(&pZ[(rloc << 7) + c2 + 1],
                           __ATOMIC_RELAXED, __HIP_MEMORY_SCOPE_AGENT);
        __syncthreads();
      }
    }
  }
}

extern "C" void kernel_launch(void* const* d_in, const int* in_sizes, int n_in,
                              void* d_out, int out_size, void* d_ws, size_t ws_size,
                              hipStream_t stream) {
  const float* x = (const float*)d_in[0];   // [256, 512, 256] f32
  const float* W = (const float*)d_in[1];   // [256, 512] f32
  float* out = (float*)d_out;               // [256*512] f32
  (void)in_sizes; (void)n_in; (void)out_size; (void)ws_size;
  // zero the epoch counters (2 KB); data regions don't need init
  hipMemsetAsync(d_ws, 0, 2048, stream);
  caps_kernel<<<512, 512, 0, stream>>>(x, W, (float*)d_out, (unsigned*)d_ws);
  (void)out;
}

// Round 9
// 1159.261 us; speedup vs baseline: 1.2039x; 1.2039x over previous
//
#include <hip/hip_runtime.h>

// Caps layer: B=256 batches, S=512 input caps, D=256 in-dim, NC=16, DC=32, O=512.
// R9 change: fix R8's launch bound. Empirical model across R1-R8: hipcc's
// __launch_bounds__ 2nd arg acts as min BLOCKS/CU (CUDA semantics):
//   (512,2) -> 16 waves/CU -> 128-VGPR budget -> 124 regs, no spill (R1/R6/R7)
//   (512,4) -> 32 waves/CU ->  64-VGPR budget -> acc spills 210 MB (R8)
// So the 2-blocks/CU split-batch experiment needs (512,2). Also: both ws
// exchanges re-mapped to lane-stride-1 (R8's stride-8 scalar loops were 8-way
// LDS-conflicted, 3.6M; also non-coalesced global).
// Structure (from R8): TWO 512-thread blocks per batch (grid=512 -> 2
// blocks/CU -> 4 waves/SIMD). Block half h owns s,o in [h*256, h*256+256).
// Coupling per iter: partial y (16KB) + half z-slab (4KB) through d_ws
// (agent-scope atomics + epoch counters). Deadlock-free: min 2 blocks/CU
// resident by construction; all 512 blocks co-resident.
// Factorized routing (u_hat never materialized):
//   y[n][D]   = sum_s c[n][s] x[s][D]     (f32 VALU, R1's exact math)
//   outputs   = squash_d( y[n] . W[:, n*32+d] )
//   z[n][D]   = sum_d W[D][n*32+d] outputs[n][d]
//   b[n][s]   = sum_D x[s][D] z[n][D]     (MFMA 16x16x32 bf16, f32 acc)

#define S_ 512
#define D_ 256
#define O_ 512

typedef __attribute__((ext_vector_type(8))) short short8;
typedef __attribute__((ext_vector_type(4))) float floatx4;

__device__ __forceinline__ unsigned short f2b(float f) {
  union { float ff; unsigned int i; } v; v.ff = f;
  unsigned int u = v.i;
  return (unsigned short)((u + 0x7FFFu + ((u >> 16) & 1u)) >> 16);
}

__global__ __launch_bounds__(512, 2) void caps_kernel(
    const float* __restrict__ x, const float* __restrict__ W,
    float* __restrict__ out, unsigned* __restrict__ ws)
{
  // LDS (35328 B; x2 blocks = 70.6 KB/CU, fits):
  //   ytmp f32 16x260 = 16640 B: y[n][D] (own partial, then full after exch)
  //   zb   u16 16x264 =  8448 B: z bf16 (528 B rows, MFMA A-frag source)
  //   outp f32 512    =  2048 B (only own half's o-range valid)
  //   cbuf f32 8x256  =  8192 B: per-wave c-tile [16n][16s]; iter-0 rowsum
  //                              strips; squash partial sums
  __shared__ __align__(16) float ytmp[16 * 260];
  __shared__ __align__(16) unsigned short zb[16 * 264];
  __shared__ __align__(16) float outp[O_];
  __shared__ __align__(16) float cbuf[8 * 256];

  const int tid  = threadIdx.x;
  const int wave = tid >> 6;
  const int lane = tid & 63;
  const int l15  = lane & 15;
  const int l4   = lane >> 4;
  const int pair = blockIdx.x >> 1;      // batch index
  const int half = blockIdx.x & 1;       // s/o half
  const int sbase = half << 8;
  const float* xb = x + (size_t)pair * (S_ * D_);

  // ws layout: ycnt[256] u32 | zcnt[256] u32 | pad to 4096B |
  //            yext [256][2][4096] f32 (8 MB) | zext [256][2][1024] u32 (2 MB)
  unsigned* ycnt = ws;
  unsigned* zcnt = ws + 256;
  float* yext = (float*)((char*)ws + 4096);
  unsigned* zext = (unsigned*)((char*)ws + 4096 + (size_t)512 * 4096 * 4);
  float* myY = yext + ((size_t)pair * 2 + half) * 4096;
  const float* pY = yext + ((size_t)pair * 2 + (half ^ 1)) * 4096;
  unsigned* myZ = zext + ((size_t)pair * 2 + half) * 1024;
  const unsigned* pZ = zext + ((size_t)pair * 2 + (half ^ 1)) * 1024;

  for (int it = 0; it < 3; ++it) {
    if (it == 0) {
      // ---- iter 0: c=1/16 uniform -> partial y = (1/16)*rowsum(own 256 s) ----
      float a0 = 0.f, a1 = 0.f, a2 = 0.f, a3 = 0.f;
      #pragma unroll 4
      for (int r = 0; r < 32; ++r) {
        const int s = sbase + (wave << 5) + r;
        const float4 xv = *(const float4*)(xb + s * D_ + (lane << 2));
        a0 += xv.x; a1 += xv.y; a2 += xv.z; a3 += xv.w;
      }
      *(float4*)(cbuf + (wave << 8) + (lane << 2)) = make_float4(a0, a1, a2, a3);
      __syncthreads();
      if (tid < 256) {
        float v = 0.f;
        #pragma unroll
        for (int w = 0; w < 8; ++w) v += cbuf[(w << 8) + tid];
        v *= 0.0625f;
        #pragma unroll
        for (int n = 0; n < 16; ++n) ytmp[n * 260 + tid] = v;
      }
      __syncthreads();
    } else {
      // ---- FUSED pass (own 256 s): per 16-s subtile: MFMA b -> softmax -> y ----
      float acc[16][4];
      #pragma unroll
      for (int n = 0; n < 16; ++n) { acc[n][0]=0.f; acc[n][1]=0.f; acc[n][2]=0.f; acc[n][3]=0.f; }
      float* cw = cbuf + (wave << 8);   // wave-private c-tile [16n][16s]

      #pragma unroll 1
      for (int t = 0; t < 2; ++t) {
        const int s0 = sbase + (wave << 5) + (t << 4);
        floatx4 C = {0.f, 0.f, 0.f, 0.f};
        #pragma unroll
        for (int k = 0; k < 8; ++k) {
          // A-frag: z[m=l15][k*32 + l4*8 + j] from LDS (full zb after exchange)
          const short8 A = *(const short8*)(zb + l15 * 264 + (k << 5) + (l4 << 3));
          // B-frag: x[s0+l15][k*32 + l4*8 + j] fp32 global -> bf16
          const float* xp = xb + (s0 + l15) * D_ + (k << 5) + (l4 << 3);
          const float4 xv0 = *(const float4*)xp;
          const float4 xv1 = *(const float4*)(xp + 4);
          short8 Bf;
          Bf[0] = (short)f2b(xv0.x); Bf[1] = (short)f2b(xv0.y);
          Bf[2] = (short)f2b(xv0.z); Bf[3] = (short)f2b(xv0.w);
          Bf[4] = (short)f2b(xv1.x); Bf[5] = (short)f2b(xv1.y);
          Bf[6] = (short)f2b(xv1.z); Bf[7] = (short)f2b(xv1.w);
          C = __builtin_amdgcn_mfma_f32_16x16x32_bf16(A, Bf, C, 0, 0, 0);
        }
        // C/D layout: col = l15 (s), row = l4*4 + rg (n).
        float m = fmaxf(fmaxf(C[0], C[1]), fmaxf(C[2], C[3]));
        m = fmaxf(m, __shfl_xor(m, 16, 64));
        m = fmaxf(m, __shfl_xor(m, 32, 64));
        const float e0 = __expf(C[0] - m), e1 = __expf(C[1] - m);
        const float e2 = __expf(C[2] - m), e3 = __expf(C[3] - m);
        float sm = e0 + e1 + e2 + e3;
        sm += __shfl_xor(sm, 16, 64);
        sm += __shfl_xor(sm, 32, 64);
        const float inv = 1.f / sm;
        const int nb = l4 << 2;
        cw[(nb + 0) * 16 + l15] = e0 * inv;
        cw[(nb + 1) * 16 + l15] = e1 * inv;
        cw[(nb + 2) * 16 + l15] = e2 * inv;
        cw[(nb + 3) * 16 + l15] = e3 * inv;
        // same-wave LDS RAW: drain writes; "memory" clobber pins ordering
        asm volatile("s_waitcnt lgkmcnt(0)" ::: "memory");
        // y-acc: lane owns D-quad; x tile re-read is L1-hot (just fetched)
        #pragma unroll 1
        for (int g = 0; g < 4; ++g) {
          const float4 xv0g = *(const float4*)(xb + (s0 + (g << 2) + 0) * D_ + (lane << 2));
          const float4 xv1g = *(const float4*)(xb + (s0 + (g << 2) + 1) * D_ + (lane << 2));
          const float4 xv2g = *(const float4*)(xb + (s0 + (g << 2) + 2) * D_ + (lane << 2));
          const float4 xv3g = *(const float4*)(xb + (s0 + (g << 2) + 3) * D_ + (lane << 2));
          #pragma unroll
          for (int n = 0; n < 16; ++n) {
            const float4 c4 = *(const float4*)(cw + n * 16 + (g << 2));  // wave-uniform b128
            acc[n][0] += c4.x * xv0g.x; acc[n][1] += c4.x * xv0g.y;
            acc[n][2] += c4.x * xv0g.z; acc[n][3] += c4.x * xv0g.w;
            acc[n][0] += c4.y * xv1g.x; acc[n][1] += c4.y * xv1g.y;
            acc[n][2] += c4.y * xv1g.z; acc[n][3] += c4.y * xv1g.w;
            acc[n][0] += c4.z * xv2g.x; acc[n][1] += c4.z * xv2g.y;
            acc[n][2] += c4.z * xv2g.z; acc[n][3] += c4.z * xv2g.w;
            acc[n][0] += c4.w * xv3g.x; acc[n][1] += c4.w * xv3g.y;
            acc[n][2] += c4.w * xv3g.z; acc[n][3] += c4.w * xv3g.w;
          }
        }
      }
      // octant reduction into ytmp (8 serialized rounds; partial y for this half)
      for (int rr = 0; rr < 8; ++rr) {
        if (wave == rr) {
          #pragma unroll
          for (int n = 0; n < 16; ++n) {
            float4* p = (float4*)(ytmp + n * 260 + (lane << 2));
            if (rr == 0) { *p = make_float4(acc[n][0], acc[n][1], acc[n][2], acc[n][3]); }
            else { float4 v = *p; v.x += acc[n][0]; v.y += acc[n][1]; v.z += acc[n][2]; v.w += acc[n][3]; *p = v; }
          }
        }
        __syncthreads();
      }
    }

    // ---- y exchange: ytmp(partial) + partner partial -> full y ----
    // lane-stride-1 mapping: conflict-free LDS, coalesced global
    {
      const int n8 = tid >> 5, c0 = tid & 31;
      #pragma unroll
      for (int j = 0; j < 8; ++j)
        __hip_atomic_store(&myY[(n8 << 8) + (j << 5) + c0],
                           ytmp[n8 * 260 + (j << 5) + c0],
                           __ATOMIC_RELAXED, __HIP_MEMORY_SCOPE_AGENT);
      __threadfence();
      __syncthreads();
      if (tid == 0) {
        __hip_atomic_fetch_add(&ycnt[pair], 1u, __ATOMIC_RELEASE, __HIP_MEMORY_SCOPE_AGENT);
        const unsigned tgt = 2u * (unsigned)(it + 1);
        while (__hip_atomic_load(&ycnt[pair], __ATOMIC_ACQUIRE, __HIP_MEMORY_SCOPE_AGENT) < tgt)
          __builtin_amdgcn_s_sleep(2);
      }
      __syncthreads();
      __threadfence();
      #pragma unroll
      for (int j = 0; j < 8; ++j)
        ytmp[n8 * 260 + (j << 5) + c0] +=
            __hip_atomic_load(&pY[(n8 << 8) + (j << 5) + c0],
                              __ATOMIC_RELAXED, __HIP_MEMORY_SCOPE_AGENT);
      __syncthreads();
    }

    // ---- squash (own 256 o, D split across thread halves p) ----
    {
      const int ol = tid & 255;
      const int p  = tid >> 8;
      const int o  = sbase + ol;
      const int n  = o >> 5;
      float a = 0.f;
      #pragma unroll 4
      for (int i = 0; i < 16; ++i) {
        const int Db = (p << 4) + i;
        const float4 y0 = *(const float4*)(ytmp + n * 260 + (Db << 3));
        const float4 y1 = *(const float4*)(ytmp + n * 260 + (Db << 3) + 4);
        const float* wp = W + (size_t)(Db << 3) * O_ + o;   // coalesced over o
        a += y0.x * wp[0 * O_]; a += y0.y * wp[1 * O_];
        a += y0.z * wp[2 * O_]; a += y0.w * wp[3 * O_];
        a += y1.x * wp[4 * O_]; a += y1.y * wp[5 * O_];
        a += y1.z * wp[6 * O_]; a += y1.w * wp[7 * O_];
      }
      if (p) cbuf[ol] = a;
      __syncthreads();
      if (!p) {
        a += cbuf[ol];
        float ss = a * a;
        #pragma unroll
        for (int off = 1; off < 32; off <<= 1) ss += __shfl_xor(ss, off, 64);
        const float v = a / sqrtf(ss + 1e-7f);
        outp[o] = v;
        if (it == 2) out[(size_t)pair * O_ + o] = v;
      }
    }
    __syncthreads();

    if (it < 2) {
      // ---- z (own 8 n): wave owns 32 D-rows, 2 rows/step via lane halves ----
      {
        const int hl    = lane & 31;
        const int rowp  = lane >> 5;
        const int obase = sbase + (hl << 3);
        const int n_ln  = (half << 3) + (hl >> 2);
        float ov[8];
        #pragma unroll
        for (int j = 0; j < 8; ++j) ov[j] = outp[obase + j];
        for (int r = 0; r < 16; ++r) {
          const int Dd = (wave << 5) + (r << 1) + rowp;
          const float4 w0 = *(const float4*)(W + (size_t)Dd * O_ + obase);
          const float4 w1 = *(const float4*)(W + (size_t)Dd * O_ + obase + 4);
          float a = w0.x * ov[0] + w0.y * ov[1] + w0.z * ov[2] + w0.w * ov[3]
                  + w1.x * ov[4] + w1.y * ov[5] + w1.z * ov[6] + w1.w * ov[7];
          a += __shfl_xor(a, 1, 64);
          a += __shfl_xor(a, 2, 64);
          if ((lane & 3) == 0) zb[n_ln * 264 + Dd] = f2b(a);
        }
      }
      __syncthreads();

      // ---- z exchange: own 8x256 slab out, partner 8x256 slab in ----
      // lane-stride-1: 1024 u32 moved by 512 threads, 2 rounds, conflict-free
      {
        const unsigned* zb32 = (const unsigned*)zb;   // rows: 132 u32 (264 u16)
        #pragma unroll
        for (int q = 0; q < 2; ++q) {
          const int idx  = (q << 9) + tid;            // 0..1023
          const int rloc = idx >> 7;                  // 0..7 local n
          const int col  = idx & 127;                 // u32 col
          const int ng   = (half << 3) + rloc;
          __hip_atomic_store(&myZ[idx], zb32[ng * 132 + col],
                             __ATOMIC_RELAXED, __HIP_MEMORY_SCOPE_AGENT);
        }
        __threadfence();
        __syncthreads();
        if (tid == 0) {
          __hip_atomic_fetch_add(&zcnt[pair], 1u, __ATOMIC_RELEASE, __HIP_MEMORY_SCOPE_AGENT);
          const unsigned tgt = 2u * (unsigned)(it + 1);
          while (__hip_atomic_load(&zcnt[pair], __ATOMIC_ACQUIRE, __HIP_MEMORY_SCOPE_AGENT) < tgt)
            __builtin_amdgcn_s_sleep(2);
        }
        __syncthreads();
        __threadfence();
        unsigned* zb32w = (unsigned*)zb;
        #pragma unroll
        for (int q = 0; q < 2; ++q) {
          const int idx  = (q << 9) + tid;
          const int rloc = idx >> 7;
          const int col  = idx & 127;
          const int np   = ((half ^ 1) << 3) + rloc;
          zb32w[np * 132 + col] = __hip_atomic_load(&pZ[idx],
                             __ATOMIC_RELAXED, __HIP_MEMORY_SCOPE_AGENT);
        }
        __syncthreads();
      }
    }
  }
}

extern "C" void kernel_launch(void* const* d_in, const int* in_sizes, int n_in,
                              void* d_out, int out_size, void* d_ws, size_t ws_size,
                              hipStream_t stream) {
  const float* x = (const float*)d_in[0];   // [256, 512, 256] f32
  const float* W = (const float*)d_in[1];   // [256, 512] f32
  (void)in_sizes; (void)n_in; (void)out_size; (void)ws_size;
  // zero the epoch counters (2 KB); data regions don't need init
  hipMemsetAsync(d_ws, 0, 2048, stream);
  caps_kernel<<<512, 512, 0, stream>>>(x, W, (float*)d_out, (unsigned*)d_ws);
}